// Round 1
// baseline (203.804 us; speedup 1.0000x reference)
//
#include <hip/hip_runtime.h>

// Problem: B=2048 batches, N=64 members, D=256, H=16.
// out[b,n] = softmax_n( relu( (N*u[b,n,:] - sum_n u[b,n,:]) * item[b,:] @ W1 + b1 ) @ W2 )
// (b2 dropped: softmax is shift-invariant.)
//
// Memory-bound: 137 MB @ 6.3 TB/s => ~21.7 us floor. One wave per batch;
// fold item into u at staging time: y'[n,h] = (u[n,:]*item) @ W1[:,h],
// z[n,h] = 64*y'[n,h] - sum_n' y'[n',h] + b1[h].

static constexpr int NMEM  = 64;
static constexpr int DDIM  = 256;
static constexpr int TD    = 32;          // d-tile width
static constexpr int NTILE = DDIM / TD;   // 8
static constexpr int UTS   = 36;          // padded LDS row stride (floats): 2-way bank alias only
static constexpr int UTS4  = UTS / 4;     // 9 (float4 stride)

__device__ __forceinline__ void fma4(float4& acc, float s, const float4& w) {
    acc.x = fmaf(s, w.x, acc.x);
    acc.y = fmaf(s, w.y, acc.y);
    acc.z = fmaf(s, w.z, acc.z);
    acc.w = fmaf(s, w.w, acc.w);
}

__global__ __launch_bounds__(256, 2)
void attn_group_softmax(const float* __restrict__ u_g,     // [B,64,256]
                        const float* __restrict__ item_g,  // [B,256]
                        const float* __restrict__ W1,      // [256,16]
                        const float* __restrict__ b1,      // [16]
                        const float* __restrict__ W2,      // [16,1]
                        float* __restrict__ out)           // [B,64]
{
    __shared__ float w1s[DDIM * 16];          // 16 KB, shared by all 4 waves
    __shared__ float item_s[4][DDIM];         // 4 KB, per-wave
    __shared__ float ut[4][NMEM * UTS];       // 36 KB, per-wave u' tile

    const int tid  = threadIdx.x;
    const int w    = tid >> 6;                // wave id 0..3
    const int lane = tid & 63;
    const int b    = blockIdx.x * 4 + w;      // one batch per wave

    // ---- stage W1 (block-wide, 4096 floats) ----
    {
        const float4* src = (const float4*)W1;
        float4* dst = (float4*)w1s;
        #pragma unroll
        for (int i = 0; i < 4; ++i) dst[tid + 256 * i] = src[tid + 256 * i];
    }
    // ---- stage item (per wave, 256 floats) ----
    {
        const float4* src = (const float4*)(item_g + (size_t)b * DDIM);
        ((float4*)item_s[w])[lane] = src[lane];
    }
    __syncthreads();

    const int q    = lane & 3;   // h-group: h = 4q..4q+3
    const int n0   = lane >> 2;  // 0..15; owns n = n0 + 16k, k=0..3
    const int col4 = lane & 7;   // staging float4 column within tile
    const int row0 = lane >> 3;  // staging row 0..7 (+8i)

    const float4* ug4  = (const float4*)u_g + (size_t)b * (NMEM * DDIM / 4);
    const float4* it4p = (const float4*)item_s[w];
    float4*       uts4 = (float4*)ut[w];
    const float4* utf4 = (const float4*)ut[w];
    const float4* w1s4 = (const float4*)w1s;

    float4 acc0 = make_float4(0.f, 0.f, 0.f, 0.f);
    float4 acc1 = acc0, acc2 = acc0, acc3 = acc0;

    // prefetch tile 0 (8 x float4 per lane = full 64x32 tile per wave)
    float4 r[8];
    #pragma unroll
    for (int i = 0; i < 8; ++i)
        r[i] = ug4[(row0 + 8 * i) * (DDIM / 4) + col4];

    for (int t = 0; t < NTILE; ++t) {
        // write tile t to LDS, folding in item
        const float4 itv = it4p[t * 8 + col4];
        #pragma unroll
        for (int i = 0; i < 8; ++i) {
            float4 v = r[i];
            v.x *= itv.x; v.y *= itv.y; v.z *= itv.z; v.w *= itv.w;
            uts4[(row0 + 8 * i) * UTS4 + col4] = v;
        }
        __syncthreads();

        // prefetch tile t+1 (overlaps the compute below; ~1024 VALU cyc > HBM latency)
        if (t + 1 < NTILE) {
            #pragma unroll
            for (int i = 0; i < 8; ++i)
                r[i] = ug4[(row0 + 8 * i) * (DDIM / 4) + (t + 1) * 8 + col4];
        }

        // compute tile t: per 4 d-columns, 8 ds_read_b128 + 64 FMA
        #pragma unroll
        for (int d4 = 0; d4 < TD / 4; ++d4) {
            const float4 ua = utf4[(n0     ) * UTS4 + d4];
            const float4 ub = utf4[(n0 + 16) * UTS4 + d4];
            const float4 uc = utf4[(n0 + 32) * UTS4 + d4];
            const float4 ud = utf4[(n0 + 48) * UTS4 + d4];
            const int dbase = (t * TD + d4 * 4) * 4 + q;
            const float4 w0  = w1s4[dbase];
            const float4 w1r = w1s4[dbase + 4];
            const float4 w2r = w1s4[dbase + 8];
            const float4 w3r = w1s4[dbase + 12];
            fma4(acc0, ua.x, w0); fma4(acc0, ua.y, w1r); fma4(acc0, ua.z, w2r); fma4(acc0, ua.w, w3r);
            fma4(acc1, ub.x, w0); fma4(acc1, ub.y, w1r); fma4(acc1, ub.z, w2r); fma4(acc1, ub.w, w3r);
            fma4(acc2, uc.x, w0); fma4(acc2, uc.y, w1r); fma4(acc2, uc.z, w2r); fma4(acc2, uc.w, w3r);
            fma4(acc3, ud.x, w0); fma4(acc3, ud.y, w1r); fma4(acc3, ud.z, w2r); fma4(acc3, ud.w, w3r);
        }
        __syncthreads();  // tile consumed; safe to overwrite next iteration
    }

    // ---- epilogue (registers + shuffles only) ----
    // ytot[h] = sum over all 64 n of y'[n,h]; lane partial = sum over its 4 n's,
    // then butterfly over the 16 lanes sharing q (XOR 4,8,16,32).
    float4 tt;
    tt.x = acc0.x + acc1.x + acc2.x + acc3.x;
    tt.y = acc0.y + acc1.y + acc2.y + acc3.y;
    tt.z = acc0.z + acc1.z + acc2.z + acc3.z;
    tt.w = acc0.w + acc1.w + acc2.w + acc3.w;
    #pragma unroll
    for (int off = 4; off <= 32; off <<= 1) {
        tt.x += __shfl_xor(tt.x, off, 64);
        tt.y += __shfl_xor(tt.y, off, 64);
        tt.z += __shfl_xor(tt.z, off, 64);
        tt.w += __shfl_xor(tt.w, off, 64);
    }

    const float4 b1v = ((const float4*)b1)[q];
    const float4 w2v = ((const float4*)W2)[q];

    auto logit_part = [&](const float4& a) -> float {
        const float zx = fmaxf(fmaf(64.f, a.x, b1v.x - tt.x), 0.f);
        const float zy = fmaxf(fmaf(64.f, a.y, b1v.y - tt.y), 0.f);
        const float zz = fmaxf(fmaf(64.f, a.z, b1v.z - tt.z), 0.f);
        const float zw = fmaxf(fmaf(64.f, a.w, b1v.w - tt.w), 0.f);
        return zx * w2v.x + zy * w2v.y + zz * w2v.z + zw * w2v.w;
    };

    float p0 = logit_part(acc0);
    float p1 = logit_part(acc1);
    float p2 = logit_part(acc2);
    float p3 = logit_part(acc3);
    // reduce over the 4 h-group lanes (XOR 1,2) -> full logits for n = n0+16k
    p0 += __shfl_xor(p0, 1, 64); p0 += __shfl_xor(p0, 2, 64);
    p1 += __shfl_xor(p1, 1, 64); p1 += __shfl_xor(p1, 2, 64);
    p2 += __shfl_xor(p2, 1, 64); p2 += __shfl_xor(p2, 2, 64);
    p3 += __shfl_xor(p3, 1, 64); p3 += __shfl_xor(p3, 2, 64);

    // softmax over 64 members distributed across 16 n0-lanes (q-replicated)
    float m = fmaxf(fmaxf(p0, p1), fmaxf(p2, p3));
    #pragma unroll
    for (int off = 4; off <= 32; off <<= 1) m = fmaxf(m, __shfl_xor(m, off, 64));
    const float e0 = __expf(p0 - m);
    const float e1 = __expf(p1 - m);
    const float e2 = __expf(p2 - m);
    const float e3 = __expf(p3 - m);
    float s = e0 + e1 + e2 + e3;
    #pragma unroll
    for (int off = 4; off <= 32; off <<= 1) s += __shfl_xor(s, off, 64);
    const float inv = 1.0f / s;

    if (q == 0) {
        float* ob = out + (size_t)b * NMEM + n0;
        ob[0]  = e0 * inv;   // each store: 16 lanes, 64 B contiguous
        ob[16] = e1 * inv;
        ob[32] = e2 * inv;
        ob[48] = e3 * inv;
    }
}

extern "C" void kernel_launch(void* const* d_in, const int* in_sizes, int n_in,
                              void* d_out, int out_size, void* d_ws, size_t ws_size,
                              hipStream_t stream) {
    const float* u    = (const float*)d_in[0];  // members_embeds [2048,64,256]
    const float* item = (const float*)d_in[1];  // item_embeds   [2048,256]
    const float* W1   = (const float*)d_in[2];  // [256,16]
    const float* b1   = (const float*)d_in[3];  // [16]
    const float* W2   = (const float*)d_in[4];  // [16,1]
    // d_in[5] = b2: dropped (softmax shift-invariant)
    (void)in_sizes; (void)n_in; (void)out_size; (void)d_ws; (void)ws_size;

    attn_group_softmax<<<512, 256, 0, stream>>>(u, item, W1, b1, W2, (float*)d_out);
}